// Round 4
// baseline (173.826 us; speedup 1.0000x reference)
//
#include <hip/hip_runtime.h>
#include <hip/hip_bf16.h>
#include <math.h>

// Problem constants
#define B_SZ   1024
#define F_SZ   1024
#define NKER   100
#define DKER   5
#define CCOLS  (NKER * DKER)   // 500
#define OUTW   (F_SZ + NKER)   // 1124
#define LOG2E_F 1.44269504088896340736f

#if defined(__has_builtin)
#if __has_builtin(__builtin_amdgcn_exp2f)
#define EXP2F(x) __builtin_amdgcn_exp2f(x)
#else
#define EXP2F(x) exp2f(x)
#endif
#else
#define EXP2F(x) exp2f(x)
#endif

// ---------------------------------------------------------------------------
// Kernel 1: copy x into out[:, :1024] and zero the feat region out[:, 1024:]
// ---------------------------------------------------------------------------
__global__ __launch_bounds__(320) void init_kernel(const float* __restrict__ x,
                                                   float* __restrict__ out) {
    const int row = blockIdx.x;
    const int t = threadIdx.x;
    if (t < 256) {
        const float4 v = *reinterpret_cast<const float4*>(&x[row * F_SZ + t * 4]);
        *reinterpret_cast<float4*>(&out[row * OUTW + t * 4]) = v;
    } else if (t < 256 + 25) {
        float4 z = make_float4(0.f, 0.f, 0.f, 0.f);
        *reinterpret_cast<float4*>(&out[row * OUTW + F_SZ + (t - 256) * 4]) = z;
    }
}

// ---------------------------------------------------------------------------
// Kernel 2a: zero mt (d_ws is poisoned 0xAA; gemm accumulates via atomics)
// 500 blocks x 256 threads x float4 = 512000 floats = CCOLS*B_SZ exactly.
// ---------------------------------------------------------------------------
__global__ __launch_bounds__(256) void zero_mt_kernel(float* __restrict__ mt) {
    const int idx = blockIdx.x * 256 + threadIdx.x;
    reinterpret_cast<float4*>(mt)[idx] = make_float4(0.f, 0.f, 0.f, 0.f);
}

// ---------------------------------------------------------------------------
// Kernel 2b: split-K fp32 GEMM, atomicAdd into mt (needs only 2 MB ws — the
// round-3 10 MB partials path likely never ran due to ws_size).
// mt[c][j] = sum_f x[j][f]*T[f][c]  (UNscaled; LOG2E folded into pair loads)
// BM=32 (c), BN=64 (j), BK=16 (f), 4 K-slices. Grid 16 x 16 x 4 = 1024 blocks
// -> 4 blocks/CU = 16 waves/CU (round-2 had 1 block/CU, VALUBusy 9.5%).
// ---------------------------------------------------------------------------
#define BMC 32
#define BNJ 64
#define BKF 16
#define NSLICE 4
#define KSLICE (F_SZ / NSLICE)   // 256

__global__ __launch_bounds__(256) void gemm_splitk_kernel(const float* __restrict__ x,
                                                          const float* __restrict__ T,
                                                          float* __restrict__ mt) {
    __shared__ float Ts[BKF][BMC];        // [f][c]
    __shared__ float Xs[BKF][BNJ + 4];    // [f][j], +4 pad keeps b128 alignment
    const int tid = threadIdx.x;
    const int c0 = blockIdx.x * BMC;
    const int j0 = blockIdx.y * BNJ;
    const int fbase = blockIdx.z * KSLICE;
    const int tcx = tid >> 4;    // 0..15 -> c sub-tile
    const int tjx = tid & 15;    // 0..15 -> j sub-tile

    float acc[2][4];
    #pragma unroll
    for (int a = 0; a < 2; ++a)
        #pragma unroll
        for (int b = 0; b < 4; ++b) acc[a][b] = 0.f;

    for (int f0 = fbase; f0 < fbase + KSLICE; f0 += BKF) {
        if (tid < 128) {
            const int r = tid >> 3;          // 0..15 (f)
            const int cc = (tid & 7) * 4;    // 0..28 (c)
            const int c = c0 + cc;
            float4 v;
            if (c + 3 < CCOLS) {
                v = *reinterpret_cast<const float4*>(&T[(f0 + r) * CCOLS + c]);
            } else {
                v.x = (c + 0 < CCOLS) ? T[(f0 + r) * CCOLS + c + 0] : 0.f;
                v.y = (c + 1 < CCOLS) ? T[(f0 + r) * CCOLS + c + 1] : 0.f;
                v.z = (c + 2 < CCOLS) ? T[(f0 + r) * CCOLS + c + 2] : 0.f;
                v.w = (c + 3 < CCOLS) ? T[(f0 + r) * CCOLS + c + 3] : 0.f;
            }
            *reinterpret_cast<float4*>(&Ts[r][cc]) = v;
        }
        {
            const int jr = tid >> 2;          // 0..63
            const int fc = (tid & 3) * 4;     // 0,4,8,12
            const float4 v =
                *reinterpret_cast<const float4*>(&x[(j0 + jr) * F_SZ + f0 + fc]);
            Xs[fc + 0][jr] = v.x;
            Xs[fc + 1][jr] = v.y;
            Xs[fc + 2][jr] = v.z;
            Xs[fc + 3][jr] = v.w;
        }
        __syncthreads();

        #pragma unroll
        for (int kk = 0; kk < BKF; ++kk) {
            const float a0 = Ts[kk][tcx * 2 + 0];
            const float a1 = Ts[kk][tcx * 2 + 1];
            const float4 b = *reinterpret_cast<const float4*>(&Xs[kk][tjx * 4]);
            acc[0][0] += a0 * b.x;
            acc[0][1] += a0 * b.y;
            acc[0][2] += a0 * b.z;
            acc[0][3] += a0 * b.w;
            acc[1][0] += a1 * b.x;
            acc[1][1] += a1 * b.y;
            acc[1][2] += a1 * b.z;
            acc[1][3] += a1 * b.w;
        }
        __syncthreads();
    }

    #pragma unroll
    for (int cc = 0; cc < 2; ++cc) {
        const int c = c0 + tcx * 2 + cc;
        if (c < CCOLS) {
            float* p = &mt[c * B_SZ + j0 + tjx * 4];
            atomicAdd(&p[0], acc[cc][0]);
            atomicAdd(&p[1], acc[cc][1]);
            atomicAdd(&p[2], acc[cc][2]);
            atomicAdd(&p[3], acc[cc][3]);
        }
    }
}

// ---------------------------------------------------------------------------
// Kernel 3: pairwise exp-L1. IPT=4 i-rows per thread, ALL state in NAMED
// scalars (round-3's m[4][5] array compiled to 24 VGPRs => rematerialized /
// spilled, ~445 cy per j-iter instead of ~100). JCHUNK=128 -> grid (8,100).
// LOG2E applied on load so the inner loop uses raw v_exp_f32 (exp2).
// ---------------------------------------------------------------------------
#define JCHUNK 128
#define JSPLIT (B_SZ / JCHUNK)   // 8

__global__ __launch_bounds__(256, 2) void pair_kernel(const float* __restrict__ mt,
                                                      float* __restrict__ out) {
    __shared__ float4 mjA[JCHUNK];   // d0..d3
    __shared__ float  mjB[JCHUNK];   // d4
    const int tid = threadIdx.x;
    const int j0 = blockIdx.x * JCHUNK;
    const int k = blockIdx.y;
    const int cb = k * DKER;

    // stage the j-chunk (5 x 128 floats), scaled by LOG2E
    for (int t = tid; t < DKER * JCHUNK; t += 256) {
        const int d = t >> 7;               // 0..4
        const int jr = t & (JCHUNK - 1);
        const float val = mt[(cb + d) * B_SZ + j0 + jr] * LOG2E_F;
        if (d < 4) reinterpret_cast<float*>(&mjA[jr])[d] = val;
        else       mjB[jr] = val;
    }

    // own points: i = tid + s*256, named scalars => guaranteed registers
    const float* r0 = &mt[(cb + 0) * B_SZ];
    const float* r1 = &mt[(cb + 1) * B_SZ];
    const float* r2 = &mt[(cb + 2) * B_SZ];
    const float* r3 = &mt[(cb + 3) * B_SZ];
    const float* r4 = &mt[(cb + 4) * B_SZ];
#define LOADM(S) \
    const float a##S##0 = r0[S * 256 + tid] * LOG2E_F; \
    const float a##S##1 = r1[S * 256 + tid] * LOG2E_F; \
    const float a##S##2 = r2[S * 256 + tid] * LOG2E_F; \
    const float a##S##3 = r3[S * 256 + tid] * LOG2E_F; \
    const float a##S##4 = r4[S * 256 + tid] * LOG2E_F;
    LOADM(0) LOADM(1) LOADM(2) LOADM(3)
#undef LOADM

    __syncthreads();

    float acc0 = 0.f, acc1 = 0.f, acc2 = 0.f, acc3 = 0.f;
    #pragma unroll 2
    for (int j = 0; j < JCHUNK; ++j) {
        const float4 v = mjA[j];
        const float  w = mjB[j];
        acc0 += EXP2F(-(fabsf(a00 - v.x) + fabsf(a01 - v.y) + fabsf(a02 - v.z) +
                        fabsf(a03 - v.w) + fabsf(a04 - w)));
        acc1 += EXP2F(-(fabsf(a10 - v.x) + fabsf(a11 - v.y) + fabsf(a12 - v.z) +
                        fabsf(a13 - v.w) + fabsf(a14 - w)));
        acc2 += EXP2F(-(fabsf(a20 - v.x) + fabsf(a21 - v.y) + fabsf(a22 - v.z) +
                        fabsf(a23 - v.w) + fabsf(a24 - w)));
        acc3 += EXP2F(-(fabsf(a30 - v.x) + fabsf(a31 - v.y) + fabsf(a32 - v.z) +
                        fabsf(a33 - v.w) + fabsf(a34 - w)));
    }

    atomicAdd(&out[(0 * 256 + tid) * OUTW + F_SZ + k], acc0);
    atomicAdd(&out[(1 * 256 + tid) * OUTW + F_SZ + k], acc1);
    atomicAdd(&out[(2 * 256 + tid) * OUTW + F_SZ + k], acc2);
    atomicAdd(&out[(3 * 256 + tid) * OUTW + F_SZ + k], acc3);
}

// ---------------------------------------------------------------------------
extern "C" void kernel_launch(void* const* d_in, const int* in_sizes, int n_in,
                              void* d_out, int out_size, void* d_ws, size_t ws_size,
                              hipStream_t stream) {
    const float* x = (const float*)d_in[0];   // [1024, 1024]
    const float* T = (const float*)d_in[1];   // [1024, 500]
    float* out = (float*)d_out;               // [1024, 1124]
    float* mt = (float*)d_ws;                 // [500][1024] fp32 = 2 MB (UNscaled)

    zero_mt_kernel<<<dim3(CCOLS), 256, 0, stream>>>(mt);
    init_kernel<<<dim3(B_SZ), 320, 0, stream>>>(x, out);
    gemm_splitk_kernel<<<dim3((CCOLS + BMC - 1) / BMC, B_SZ / BNJ, NSLICE),
                         256, 0, stream>>>(x, T, mt);
    pair_kernel<<<dim3(JSPLIT, NKER), 256, 0, stream>>>(mt, out);
}

// Round 5
// 151.547 us; speedup vs baseline: 1.1470x; 1.1470x over previous
//
#include <hip/hip_runtime.h>
#include <hip/hip_bf16.h>
#include <math.h>

// Problem constants
#define B_SZ   1024
#define F_SZ   1024
#define NKER   100
#define DKER   5
#define CCOLS  (NKER * DKER)   // 500
#define OUTW   (F_SZ + NKER)   // 1124
#define LOG2E_F 1.44269504088896340736f

#if defined(__has_builtin)
#if __has_builtin(__builtin_amdgcn_exp2f)
#define EXP2F(x) __builtin_amdgcn_exp2f(x)
#else
#define EXP2F(x) exp2f(x)
#endif
#else
#define EXP2F(x) exp2f(x)
#endif

typedef __attribute__((ext_vector_type(8))) short bf16x8;
typedef __attribute__((ext_vector_type(4))) float f32x4;
typedef __attribute__((ext_vector_type(4))) short short4v;
typedef __attribute__((ext_vector_type(8))) short short8v;

// f32 -> bf16 round-to-nearest-even (data is well-behaved normals; no NaN path)
__device__ __forceinline__ short f2bf(float f) {
    unsigned int u = __float_as_uint(f);
    u += 0x7FFFu + ((u >> 16) & 1u);
    return (short)(u >> 16);
}

// ---------------------------------------------------------------------------
// Kernel 1: copy x into out[:, :1024] and zero the feat region out[:, 1024:]
// ---------------------------------------------------------------------------
__global__ __launch_bounds__(320) void init_kernel(const float* __restrict__ x,
                                                   float* __restrict__ out) {
    const int row = blockIdx.x;
    const int t = threadIdx.x;
    if (t < 256) {
        const float4 v = *reinterpret_cast<const float4*>(&x[row * F_SZ + t * 4]);
        *reinterpret_cast<float4*>(&out[row * OUTW + t * 4]) = v;
    } else if (t < 256 + 25) {
        float4 z = make_float4(0.f, 0.f, 0.f, 0.f);
        *reinterpret_cast<float4*>(&out[row * OUTW + F_SZ + (t - 256) * 4]) = z;
    }
}

// ---------------------------------------------------------------------------
// Kernel 2: bf16 MFMA GEMM  mt[c][j] = sum_f x[j][f] * T[f][c]  (fp32 out)
// Precision note: feat = 1 + sum exp(-l1), typical l1 ~ 180 -> bf16 m-error
// (±0.5 on l1) is invisible; self term stays exact (mt[i]-mt[i] == 0).
// C = A * B with A[c][f] = T^T (staged via LDS transpose+cvt), B[f][j] = x^T
// (x rows are K-major already). mfma_f32_16x16x32_bf16; A/B frag: lane l
// holds 8 contiguous k at row/col = l&15, kchunk = (l>>4)*8. C/D: col=lane&15,
// row=(lane>>4)*4+reg (m89-verified).
// Tile: 32c x 64j, BK=32, grid (512/32, 1024/64) = 16x16 = 256 blocks (1/CU).
// Global->reg loads for step s+1 issued before compute of step s (latency hidden).
// ---------------------------------------------------------------------------
#define GBM 32
#define GBN 64
#define GBK 32
#define NSTEP (F_SZ / GBK)   // 32
#define APAD 40              // LDS row length in bf16: 32 + 8 pad (80 B rows, 16B-aligned)

__global__ __launch_bounds__(256) void gemm_mfma_kernel(const float* __restrict__ x,
                                                        const float* __restrict__ T,
                                                        float* __restrict__ mt) {
    __shared__ short Al[GBM][APAD];   // [c][k] bf16
    __shared__ short Bl[GBN][APAD];   // [j][k] bf16
    const int tid = threadIdx.x;
    const int l = tid & 63;
    const int w = tid >> 6;            // wave 0..3 -> j sub-tile
    const int c0 = blockIdx.x * GBM;
    const int j0 = blockIdx.y * GBN;

    // A staging map: thread -> (c-offset acc_, k-base arB), 4 elems each
    const int acc_ = tid & 31;
    const int arB = (tid >> 5) * 4;
    const bool aval = (c0 + acc_) < CCOLS;
    // B staging map: thread -> (j-offset bjr, k-base bfc), 8 elems each
    const int bjr = tid >> 2;
    const int bfc = (tid & 3) * 8;

    float aF0, aF1, aF2, aF3;
    float4 bF0, bF1;

    // prologue: global loads for step 0 (A: coalesced over c; B: float4 over f)
    {
        const float* tp = &T[(0 + arB) * CCOLS + c0 + acc_];
        aF0 = aval ? tp[0 * CCOLS] : 0.f;
        aF1 = aval ? tp[1 * CCOLS] : 0.f;
        aF2 = aval ? tp[2 * CCOLS] : 0.f;
        aF3 = aval ? tp[3 * CCOLS] : 0.f;
        const float* xp = &x[(j0 + bjr) * F_SZ + 0 + bfc];
        bF0 = *reinterpret_cast<const float4*>(xp);
        bF1 = *reinterpret_cast<const float4*>(xp + 4);
    }

    f32x4 acc0 = {0.f, 0.f, 0.f, 0.f};
    f32x4 acc1 = {0.f, 0.f, 0.f, 0.f};

    const int fr = (l >> 4) * 8;       // k-chunk base for frags
    const int arow0 = (l & 15);        // A rows for ct=0 / ct=1
    const int brow = w * 16 + (l & 15);

    for (int s = 0; s < NSTEP; ++s) {
        if (s) __syncthreads();        // previous step's frag reads done
        // cvt + LDS write (consumes regs loaded last step)
        {
            short4v aw;
            aw.x = f2bf(aF0); aw.y = f2bf(aF1); aw.z = f2bf(aF2); aw.w = f2bf(aF3);
            *reinterpret_cast<short4v*>(&Al[acc_][arB]) = aw;
            short8v bw;
            bw.s0 = f2bf(bF0.x); bw.s1 = f2bf(bF0.y); bw.s2 = f2bf(bF0.z); bw.s3 = f2bf(bF0.w);
            bw.s4 = f2bf(bF1.x); bw.s5 = f2bf(bF1.y); bw.s6 = f2bf(bF1.z); bw.s7 = f2bf(bF1.w);
            *reinterpret_cast<short8v*>(&Bl[bjr][bfc]) = bw;
        }
        __syncthreads();
        // issue next step's global loads (waited at next iter's cvt -> hidden)
        if (s + 1 < NSTEP) {
            const int f0 = (s + 1) * GBK;
            const float* tp = &T[(f0 + arB) * CCOLS + c0 + acc_];
            aF0 = aval ? tp[0 * CCOLS] : 0.f;
            aF1 = aval ? tp[1 * CCOLS] : 0.f;
            aF2 = aval ? tp[2 * CCOLS] : 0.f;
            aF3 = aval ? tp[3 * CCOLS] : 0.f;
            const float* xp = &x[(j0 + bjr) * F_SZ + f0 + bfc];
            bF0 = *reinterpret_cast<const float4*>(xp);
            bF1 = *reinterpret_cast<const float4*>(xp + 4);
        }
        // fragments + MFMA
        const bf16x8 bfrag = *reinterpret_cast<const bf16x8*>(&Bl[brow][fr]);
        const bf16x8 af0 = *reinterpret_cast<const bf16x8*>(&Al[arow0][fr]);
        const bf16x8 af1 = *reinterpret_cast<const bf16x8*>(&Al[16 + arow0][fr]);
        acc0 = __builtin_amdgcn_mfma_f32_16x16x32_bf16(af0, bfrag, acc0, 0, 0, 0);
        acc1 = __builtin_amdgcn_mfma_f32_16x16x32_bf16(af1, bfrag, acc1, 0, 0, 0);
    }

    // store: c = c0 + ct*16 + (l>>4)*4 + q ; j = j0 + w*16 + (l&15)
    const int jst = j0 + w * 16 + (l & 15);
    const int crow = c0 + ((l >> 4) * 4);
    #pragma unroll
    for (int q = 0; q < 4; ++q) {
        const int cA = crow + q;
        if (cA < CCOLS) mt[cA * B_SZ + jst] = acc0[q];
        const int cB = crow + 16 + q;
        if (cB < CCOLS) mt[cB * B_SZ + jst] = acc1[q];
    }
}

// ---------------------------------------------------------------------------
// Kernel 3: pairwise exp-L1. IPT=4 i per thread; inner loop handles 4 j per
// iteration via one ds_read_b128 per d-plane (broadcast, conflict-free) ->
// LDS instrs per pair 0.5 -> 0.31 and 4x the VALU per LDS latency. i-point
// values pinned in VGPRs via asm (round-3/4: allocator remat'd them -> 74us).
// ---------------------------------------------------------------------------
#define JCHUNK 128
#define JSPLIT (B_SZ / JCHUNK)   // 8

__global__ __launch_bounds__(256) void pair_kernel(const float* __restrict__ mt,
                                                   float* __restrict__ out) {
    __shared__ float mj[DKER][JCHUNK];
    const int tid = threadIdx.x;
    const int j0 = blockIdx.x * JCHUNK;
    const int k = blockIdx.y;
    const int cb = k * DKER;

    // stage the j-chunk (5 x 128 floats), scaled by LOG2E
    for (int t = tid; t < DKER * JCHUNK; t += 256) {
        const int d = t >> 7;
        const int jr = t & (JCHUNK - 1);
        mj[d][jr] = mt[(cb + d) * B_SZ + j0 + jr] * LOG2E_F;
    }

    const float* r0 = &mt[(cb + 0) * B_SZ];
    const float* r1 = &mt[(cb + 1) * B_SZ];
    const float* r2 = &mt[(cb + 2) * B_SZ];
    const float* r3 = &mt[(cb + 3) * B_SZ];
    const float* r4 = &mt[(cb + 4) * B_SZ];
#define LOADM(S) \
    float a##S##0 = r0[S * 256 + tid] * LOG2E_F; \
    float a##S##1 = r1[S * 256 + tid] * LOG2E_F; \
    float a##S##2 = r2[S * 256 + tid] * LOG2E_F; \
    float a##S##3 = r3[S * 256 + tid] * LOG2E_F; \
    float a##S##4 = r4[S * 256 + tid] * LOG2E_F;
    LOADM(0) LOADM(1) LOADM(2) LOADM(3)
#undef LOADM
    // pin the 20 i-point values in VGPRs (defeat rematerialization/spill)
    asm volatile("" : "+v"(a00), "+v"(a01), "+v"(a02), "+v"(a03), "+v"(a04),
                      "+v"(a10), "+v"(a11), "+v"(a12), "+v"(a13), "+v"(a14));
    asm volatile("" : "+v"(a20), "+v"(a21), "+v"(a22), "+v"(a23), "+v"(a24),
                      "+v"(a30), "+v"(a31), "+v"(a32), "+v"(a33), "+v"(a34));

    __syncthreads();

    float acc0 = 0.f, acc1 = 0.f, acc2 = 0.f, acc3 = 0.f;
    #pragma unroll 2
    for (int jb = 0; jb < JCHUNK / 4; ++jb) {
        const float4 q0 = *reinterpret_cast<const float4*>(&mj[0][jb * 4]);
        const float4 q1 = *reinterpret_cast<const float4*>(&mj[1][jb * 4]);
        const float4 q2 = *reinterpret_cast<const float4*>(&mj[2][jb * 4]);
        const float4 q3 = *reinterpret_cast<const float4*>(&mj[3][jb * 4]);
        const float4 q4 = *reinterpret_cast<const float4*>(&mj[4][jb * 4]);
#define DOJ(C) { \
        const float b0 = q0.C, b1 = q1.C, b2 = q2.C, b3 = q3.C, b4 = q4.C; \
        acc0 += EXP2F(-(fabsf(a00 - b0) + fabsf(a01 - b1) + fabsf(a02 - b2) + \
                        fabsf(a03 - b3) + fabsf(a04 - b4))); \
        acc1 += EXP2F(-(fabsf(a10 - b0) + fabsf(a11 - b1) + fabsf(a12 - b2) + \
                        fabsf(a13 - b3) + fabsf(a14 - b4))); \
        acc2 += EXP2F(-(fabsf(a20 - b0) + fabsf(a21 - b1) + fabsf(a22 - b2) + \
                        fabsf(a23 - b3) + fabsf(a24 - b4))); \
        acc3 += EXP2F(-(fabsf(a30 - b0) + fabsf(a31 - b1) + fabsf(a32 - b2) + \
                        fabsf(a33 - b3) + fabsf(a34 - b4))); }
        DOJ(x) DOJ(y) DOJ(z) DOJ(w)
#undef DOJ
    }

    atomicAdd(&out[(0 * 256 + tid) * OUTW + F_SZ + k], acc0);
    atomicAdd(&out[(1 * 256 + tid) * OUTW + F_SZ + k], acc1);
    atomicAdd(&out[(2 * 256 + tid) * OUTW + F_SZ + k], acc2);
    atomicAdd(&out[(3 * 256 + tid) * OUTW + F_SZ + k], acc3);
}

// ---------------------------------------------------------------------------
extern "C" void kernel_launch(void* const* d_in, const int* in_sizes, int n_in,
                              void* d_out, int out_size, void* d_ws, size_t ws_size,
                              hipStream_t stream) {
    const float* x = (const float*)d_in[0];   // [1024, 1024]
    const float* T = (const float*)d_in[1];   // [1024, 500]
    float* out = (float*)d_out;               // [1024, 1124]
    float* mt = (float*)d_ws;                 // [500][1024] fp32 = 2 MB (known-safe ws)

    init_kernel<<<dim3(B_SZ), 320, 0, stream>>>(x, out);
    gemm_mfma_kernel<<<dim3(512 / GBM, B_SZ / GBN), 256, 0, stream>>>(x, T, mt);
    pair_kernel<<<dim3(JSPLIT, NKER), 256, 0, stream>>>(mt, out);
}